// Round 1
// baseline (504.806 us; speedup 1.0000x reference)
//
#include <hip/hip_runtime.h>
#include <hip/hip_bf16.h>
#include <math.h>

// B=16 L=512 K=48 E=128 D=384 H=128
#define NB 16
#define NL 512
#define NK 48
#define NE 128
#define ND 384
#define NH 128

typedef __attribute__((ext_vector_type(8))) short short8;
typedef __attribute__((ext_vector_type(4))) float f32x4;

// fast erf-gelu: tanh-form reduced to sigmoid, sigmoid via hw exp2 + rcp.
__device__ __forceinline__ float gelu_fast(float x) {
    float t = x * fmaf(x * x, -0.1029437f, -2.3022087f);
    float e = __builtin_amdgcn_exp2f(t);
    return x * __builtin_amdgcn_rcpf(1.0f + e);
}

// round-to-nearest-even f32 -> bf16 bits
__device__ __forceinline__ unsigned short f2bf(float x) {
    union { float f; unsigned u; } v; v.f = x;
    unsigned r = v.u + 0x7fffu + ((v.u >> 16) & 1u);
    return (unsigned short)(r >> 16);
}

// cheap round-half-up f32 -> bf16 bits (2 inst)
__device__ __forceinline__ unsigned short f2bf_rhu(float x) {
    union { float f; unsigned u; } v; v.f = x;
    return (unsigned short)((v.u + 0x8000u) >> 16);
}

// pack two f32 -> (bf16(a)<<16)|bf16(b), round-half-up: 2 adds + 1 v_perm
__device__ __forceinline__ unsigned pk_bf16(float a, float b) {
    union { float f; unsigned u; } ua, ub; ua.f = a; ub.f = b;
    return __builtin_amdgcn_perm(ua.u + 0x8000u, ub.u + 0x8000u, 0x07060302u);
}

// ---------------------------------------------------------------------------
// Kernel 0: pack fw1/fw2/hw1/hw2 into bf16 MFMA fragment order:
// dst[((kt*NT+nt)*64 + quad*16 + nc)*8 + j], kt=k>>5, quad=(k>>3)&3, j=k&7,
// nt=n>>4, nc=n&15.
// v2: one thread packs a full j=0..7 fragment (16B write). Reads are
// row-coalesced (lanes span consecutive n), writes are fully coalesced
// (consecutive lanes -> consecutive 16B fragments).
// Thread counts: fw1 (128/8)*384=6144, fw2 (384/8)*384=18432,
// hw1 (384/8)*128=6144, hw2 (128/8)*64=1024 -> total 31744 = 124*256.
// ---------------------------------------------------------------------------
__global__ void pack_weights(const float* __restrict__ fw1,
                             const float* __restrict__ fw2,
                             const float* __restrict__ hw1,
                             const float* __restrict__ hw2,
                             unsigned short* __restrict__ fw1p,
                             unsigned short* __restrict__ fw2p,
                             unsigned short* __restrict__ hw1p,
                             unsigned short* __restrict__ hw2p) {
    int tid = blockIdx.x * 256 + threadIdx.x;
    const float* src; unsigned short* dst; int N, NT, idx;
    if (tid < 6144)        { src = fw1; dst = fw1p; N = ND;     NT = 24; idx = tid; }
    else if (tid < 24576)  { src = fw2; dst = fw2p; N = ND;     NT = 24; idx = tid - 6144; }
    else if (tid < 30720)  { src = hw1; dst = hw1p; N = NH;     NT = 8;  idx = tid - 24576; }
    else                   { src = hw2; dst = hw2p; N = NH / 2; NT = 4;  idx = tid - 30720; }
    int kg = idx / N;
    int n  = idx - kg * N;
    int k0 = kg * 8;
    int base = (((k0 >> 5) * NT + (n >> 4)) * 64 + ((k0 >> 3) & 3) * 16 + (n & 15)) * 8;
    short8 v;
    #pragma unroll
    for (int j = 0; j < 8; j++)
        v[j] = (short)f2bf(src[(size_t)(k0 + j) * N + n]);
    *(short8*)(dst + base) = v;
}

// ---------------------------------------------------------------------------
// Kernel 1: fused CFConv.  One block = 1 (b,l) group = 48 edge-rows.
// GEMM1 (transposed: D^T = fw1^T @ h_E^T) [384x128]@[128x48] -> gelu ->
// bf16 T via ds_write_b64 -> GEMM2 [48x384]@[384x384] (dbuf B prefetch) ->
// epilogue: bias+gelu -> W, gather x_j = h_V[E_idx], reduce over k.
// v2: Ea aliases T (Ea dead after GEMM1 MFMAs; one extra barrier) ->
// LDS 37.8KB -> 4 blocks/CU (was 51KB / 3 blocks). Occupancy 31%->42%.
// ---------------------------------------------------------------------------
__global__ __launch_bounds__(256, 4) void cfconv_kernel(
    const float* __restrict__ h_V, const float* __restrict__ h_E,
    const float* __restrict__ fb1, const float* __restrict__ fb2,
    const unsigned short* __restrict__ fw1p,
    const unsigned short* __restrict__ fw2p,
    const int* __restrict__ E_idx, unsigned short* __restrict__ hbufB)
{
    // Single buffer, two phases:
    //   phase 1: Ea = h_E tile, 48 x 136 bf16 (6528 shorts)
    //   phase 2: T  = gelu(GEMM1) tile, 48 x 392 bf16 (18816 shorts)
    __shared__ unsigned short SH[48 * 392];
    __shared__ int rowoff_s[48];
    unsigned short* const Ea = SH;
    unsigned short* const T  = SH;

    const int t = threadIdx.x;
    const int wave = t >> 6, lane = t & 63;
    const int quad = lane >> 4, l16 = lane & 15;
    const int bl = blockIdx.x;
    const int wn0 = wave * 96;   // this wave's column slice of 384

    if (t < 48)
        rowoff_s[t] = ((bl >> 9) * NL + E_idx[bl * NK + t]) * ND;

    // stage h_E (48x128 f32) -> bf16 Ea
    {
        const float4* src = (const float4*)(h_E + (size_t)bl * (NK * NE));
        #pragma unroll
        for (int i = 0; i < 6; i++) {
            int v = i * 256 + t;         // 1536 float4
            float4 d = src[v];
            int r = v >> 5;              // 32 float4 per 128-col row
            int c = (v & 31) * 4;
            uint2 u;
            u.x = pk_bf16(d.y, d.x);
            u.y = pk_bf16(d.w, d.z);
            *(uint2*)&Ea[r * 136 + c] = u;
        }
    }
    __syncthreads();

    f32x4 acc[18];

    // ---- GEMM1 (transposed): M=n (wave slice 96, 6 mt), N=edge (48, 3 nt),
    //      K=128 (4 kt).  A = fw1^T from fw1p; B = h_E^T from Ea.
    #pragma unroll
    for (int i = 0; i < 18; i++) acc[i] = (f32x4){0.f, 0.f, 0.f, 0.f};

    #pragma unroll
    for (int kt = 0; kt < 4; kt++) {
        short8 aw[6], be[3];
        #pragma unroll
        for (int mt = 0; mt < 6; mt++)
            aw[mt] = *(const short8*)(fw1p + (size_t)((kt * 24 + (wn0 >> 4) + mt) * 64 + lane) * 8);
        #pragma unroll
        for (int nt = 0; nt < 3; nt++)
            be[nt] = *(const short8*)&Ea[(nt * 16 + l16) * 136 + kt * 32 + quad * 8];
        #pragma unroll
        for (int mt = 0; mt < 6; mt++)
            #pragma unroll
            for (int nt = 0; nt < 3; nt++)
                acc[mt * 3 + nt] = __builtin_amdgcn_mfma_f32_16x16x32_bf16(
                    aw[mt], be[nt], acc[mt * 3 + nt], 0, 0, 0);
    }

    // All Ea reads are done; T aliases Ea, so barrier before overwriting.
    __syncthreads();

    // epilogue1: +fb1, gelu -> T.  C/D of transposed GEMM1: col=edge (l16),
    // row = n-within-tile (quad*4+r): 4 consecutive n per lane -> b64 writes.
    #pragma unroll
    for (int mt = 0; mt < 6; mt++) {
        float4 b1v = *(const float4*)&fb1[wn0 + mt * 16 + quad * 4];
        #pragma unroll
        for (int nt = 0; nt < 3; nt++) {
            f32x4 a = acc[mt * 3 + nt];
            float v0 = gelu_fast(a[0] + b1v.x);
            float v1 = gelu_fast(a[1] + b1v.y);
            float v2 = gelu_fast(a[2] + b1v.z);
            float v3 = gelu_fast(a[3] + b1v.w);
            uint2 u;
            u.x = pk_bf16(v1, v0);
            u.y = pk_bf16(v3, v2);
            *(uint2*)&T[(nt * 16 + l16) * 392 + wn0 + mt * 16 + quad * 4] = u;
        }
    }
    __syncthreads();

    // ---- GEMM2: M=edge (48, 3 mt), N=wave slice 96 (6 nt), K=384 (12 kt),
    //      double-buffered B prefetch.
    #pragma unroll
    for (int i = 0; i < 18; i++) acc[i] = (f32x4){0.f, 0.f, 0.f, 0.f};

    {
        short8 b0[6], b1[6], af[3];
        #define LOADB(kt, bf)                                                            \
            _Pragma("unroll")                                                            \
            for (int nt = 0; nt < 6; nt++)                                               \
                bf[nt] = *(const short8*)(fw2p +                                         \
                    (size_t)(((kt) * 24 + (wn0 >> 4) + nt) * 64 + lane) * 8);
        #define LOADA(kt)                                                                \
            _Pragma("unroll")                                                            \
            for (int mt = 0; mt < 3; mt++)                                               \
                af[mt] = *(const short8*)&T[(mt * 16 + l16) * 392 + (kt) * 32 + quad * 8];
        #define MFMAS(bf)                                                                \
            _Pragma("unroll")                                                            \
            for (int mt = 0; mt < 3; mt++)                                               \
                _Pragma("unroll")                                                        \
                for (int nt = 0; nt < 6; nt++)                                           \
                    acc[nt * 3 + mt] = __builtin_amdgcn_mfma_f32_16x16x32_bf16(          \
                        af[mt], bf[nt], acc[nt * 3 + mt], 0, 0, 0);

        LOADB(0, b0);
        for (int kt = 0; kt < 10; kt += 2) {
            LOADB(kt + 1, b1);
            LOADA(kt);
            MFMAS(b0);
            LOADB(kt + 2, b0);
            LOADA(kt + 1);
            MFMAS(b1);
        }
        LOADB(11, b1);
        LOADA(10);
        MFMAS(b0);
        LOADA(11);
        MFMAS(b1);
        #undef LOADB
        #undef LOADA
        #undef MFMAS
    }

    // epilogue2: +fb2, gelu -> W; gather x_j; reduce over all 48 rows; store.
    float b2v[6];
    #pragma unroll
    for (int nt = 0; nt < 6; nt++) b2v[nt] = fb2[wn0 + nt * 16 + l16];

    float s[6] = {0.f, 0.f, 0.f, 0.f, 0.f, 0.f};
    #pragma unroll
    for (int mt = 0; mt < 3; mt++) {
        const int rb = mt * 16 + quad * 4;
        const float* p0 = h_V + rowoff_s[rb + 0] + wn0 + l16;
        const float* p1 = h_V + rowoff_s[rb + 1] + wn0 + l16;
        const float* p2 = h_V + rowoff_s[rb + 2] + wn0 + l16;
        const float* p3 = h_V + rowoff_s[rb + 3] + wn0 + l16;
        float xv[6][4];
        #pragma unroll
        for (int nt = 0; nt < 6; nt++) {
            xv[nt][0] = p0[nt * 16];
            xv[nt][1] = p1[nt * 16];
            xv[nt][2] = p2[nt * 16];
            xv[nt][3] = p3[nt * 16];
        }
        #pragma unroll
        for (int nt = 0; nt < 6; nt++)
            #pragma unroll
            for (int r = 0; r < 4; r++)
                s[nt] = fmaf(gelu_fast(acc[nt * 3 + mt][r] + b2v[nt]), xv[nt][r], s[nt]);
    }
    #pragma unroll
    for (int nt = 0; nt < 6; nt++) {
        float v = s[nt];
        v += __shfl_xor(v, 16, 64);
        v += __shfl_xor(v, 32, 64);
        if (lane < 16)
            hbufB[(size_t)bl * ND + wn0 + nt * 16 + lane] = f2bf(v);
    }
}

// ---------------------------------------------------------------------------
// Kernel 2: MLP head via MFMA.
// v2: two waves per 16-row tile (block=128 thr), splitting the N dimension:
// layer1 N=128 -> 64 cols/wave; layer2 N=64 -> 32 cols/wave; layer3 dot is
// split by column, combined via the separability of the masked row-sum
// (each wave contributes mask*(partial_pr + hb3/2)). 1024 waves total
// (2x the parallelism of v1's 512 one-wave blocks).
// ---------------------------------------------------------------------------
__global__ __launch_bounds__(128) void head_kernel(
    const unsigned short* __restrict__ hbufB,
    const unsigned short* __restrict__ hw1p, const float* __restrict__ hb1,
    const unsigned short* __restrict__ hw2p, const float* __restrict__ hb2,
    const float* __restrict__ hw3, const float* __restrict__ hb3,
    const float* __restrict__ mask, float* __restrict__ dGpart)
{
    __shared__ unsigned short T1[16 * 136];
    const int t = threadIdx.x;
    const int w = t >> 6;                 // wave id 0/1
    const int lane = t & 63;
    const int quad = lane >> 4, l16 = lane & 15;
    const int row0 = blockIdx.x * 16;

    // ---- layer1: K=384; this wave covers cols [w*64, w*64+64) ----
    f32x4 acc1[4];
    #pragma unroll
    for (int nt = 0; nt < 4; nt++) acc1[nt] = (f32x4){0.f, 0.f, 0.f, 0.f};

    for (int kt = 0; kt < 12; kt++) {
        short8 a = *(const short8*)(hbufB + (size_t)(row0 + l16) * ND + kt * 32 + quad * 8);
        #pragma unroll
        for (int nt = 0; nt < 4; nt++) {
            short8 b = *(const short8*)(hw1p + (size_t)((kt * 8 + w * 4 + nt) * 64 + lane) * 8);
            acc1[nt] = __builtin_amdgcn_mfma_f32_16x16x32_bf16(a, b, acc1[nt], 0, 0, 0);
        }
    }

    // gelu + bias -> T1 bf16 (waves write disjoint column halves)
    #pragma unroll
    for (int nt = 0; nt < 4; nt++) {
        int col = (w * 4 + nt) * 16 + l16;
        float b1 = hb1[col];
        #pragma unroll
        for (int r = 0; r < 4; r++)
            T1[(quad * 4 + r) * 136 + col] = f2bf_rhu(gelu_fast(acc1[nt][r] + b1));
    }
    __syncthreads();

    // ---- layer2: K=128; this wave covers cols [w*32, w*32+32) ----
    f32x4 acc2[2];
    #pragma unroll
    for (int nt = 0; nt < 2; nt++) acc2[nt] = (f32x4){0.f, 0.f, 0.f, 0.f};

    #pragma unroll
    for (int kt = 0; kt < 4; kt++) {
        short8 a = *(const short8*)&T1[l16 * 136 + kt * 32 + quad * 8];
        #pragma unroll
        for (int nt = 0; nt < 2; nt++) {
            short8 b = *(const short8*)(hw2p + (size_t)((kt * 4 + w * 2 + nt) * 64 + lane) * 8);
            acc2[nt] = __builtin_amdgcn_mfma_f32_16x16x32_bf16(a, b, acc2[nt], 0, 0, 0);
        }
    }

    // ---- layer3: gelu then partial 32-dot + masked accumulation ----
    float w3[2], b2[2];
    #pragma unroll
    for (int nt = 0; nt < 2; nt++) {
        int col = (w * 2 + nt) * 16 + l16;
        w3[nt] = hw3[col];
        b2[nt] = hb2[col];
    }

    float dsum = 0.f;
    const float hb3h = 0.5f * hb3[0];     // split evenly across the 2 waves
    #pragma unroll
    for (int r = 0; r < 4; r++) {
        float pr = 0.f;
        #pragma unroll
        for (int nt = 0; nt < 2; nt++)
            pr = fmaf(gelu_fast(acc2[nt][r] + b2[nt]), w3[nt], pr);
        pr += __shfl_xor(pr, 1, 64);
        pr += __shfl_xor(pr, 2, 64);
        pr += __shfl_xor(pr, 4, 64);
        pr += __shfl_xor(pr, 8, 64);
        if (l16 == 0) {
            int grow = row0 + quad * 4 + r;
            dsum = fmaf(pr + hb3h, mask[grow], dsum);
        }
    }
    dsum += __shfl_xor(dsum, 16, 64);
    dsum += __shfl_xor(dsum, 32, 64);
    if (lane == 0) dGpart[blockIdx.x * 2 + w] = dsum;
}

// ---------------------------------------------------------------------------
// Kernel 3: out[b] = sum(dGpart[b*64..b*64+64)) / sqrt(clip(sum(mask[b,:]),1))
// 256 threads: 16 lanes per batch
// ---------------------------------------------------------------------------
__global__ void finalize_kernel(const float* __restrict__ dGpart,
                                const float* __restrict__ mask,
                                float* __restrict__ out) {
    int t = threadIdx.x;
    int b = t >> 4, j = t & 15;
    float ms = 0.f;
    for (int l = j; l < NL; l += 16) ms += mask[b * NL + l];
    float dg = dGpart[b * 64 + j] + dGpart[b * 64 + 16 + j]
             + dGpart[b * 64 + 32 + j] + dGpart[b * 64 + 48 + j];
    #pragma unroll
    for (int d = 1; d < 16; d <<= 1) {
        ms += __shfl_xor(ms, d, 64);
        dg += __shfl_xor(dg, d, 64);
    }
    if (j == 0) {
        ms = fmaxf(ms, 1.0f);
        out[b] = dg / sqrtf(ms);
    }
}

extern "C" void kernel_launch(void* const* d_in, const int* in_sizes, int n_in,
                              void* d_out, int out_size, void* d_ws, size_t ws_size,
                              hipStream_t stream) {
    const float* h_V  = (const float*)d_in[0];
    const float* h_E  = (const float*)d_in[1];
    const float* mask = (const float*)d_in[2];
    const float* fw1  = (const float*)d_in[3];
    const float* fb1  = (const float*)d_in[4];
    const float* fw2  = (const float*)d_in[5];
    const float* fb2  = (const float*)d_in[6];
    const float* hw1  = (const float*)d_in[7];
    const float* hb1  = (const float*)d_in[8];
    const float* hw2  = (const float*)d_in[9];
    const float* hb2  = (const float*)d_in[10];
    const float* hw3  = (const float*)d_in[11];
    const float* hb3  = (const float*)d_in[12];
    const int*   E_idx = (const int*)d_in[13];
    float* out = (float*)d_out;

    char* ws = (char*)d_ws;
    unsigned short* fw1p = (unsigned short*)ws;              // 128*384*2 =  98304 B
    unsigned short* fw2p = (unsigned short*)(ws + 98304);    // 384*384*2 = 294912 B
    unsigned short* hw1p = (unsigned short*)(ws + 393216);   // 384*128*2 =  98304 B
    unsigned short* hw2p = (unsigned short*)(ws + 491520);   // 128*64*2  =  16384 B
    float* dGpart = (float*)(ws + 507904);                   // 1024*4 = 4096 B
    unsigned short* hbufB = (unsigned short*)(ws + 512000);  // 8192*384*2 = 6.3 MB

    pack_weights<<<124, 256, 0, stream>>>(fw1, fw2, hw1, hw2, fw1p, fw2p, hw1p, hw2p);
    cfconv_kernel<<<NB * NL, 256, 0, stream>>>(h_V, h_E, fb1, fb2, fw1p, fw2p, E_idx, hbufB);
    head_kernel<<<(NB * NL) / 16, 128, 0, stream>>>(hbufB, hw1p, hb1, hw2p, hb2, hw3, hb3, mask, dGpart);
    finalize_kernel<<<1, 256, 0, stream>>>(dGpart, mask, out);
}

// Round 2
// 453.011 us; speedup vs baseline: 1.1143x; 1.1143x over previous
//
#include <hip/hip_runtime.h>
#include <hip/hip_bf16.h>
#include <math.h>

// B=16 L=512 K=48 E=128 D=384 H=128
#define NB 16
#define NL 512
#define NK 48
#define NE 128
#define ND 384
#define NH 128

typedef __attribute__((ext_vector_type(8))) short short8;
typedef __attribute__((ext_vector_type(4))) float f32x4;

// fast erf-gelu: tanh-form reduced to sigmoid, sigmoid via hw exp2 + rcp.
__device__ __forceinline__ float gelu_fast(float x) {
    float t = x * fmaf(x * x, -0.1029437f, -2.3022087f);
    float e = __builtin_amdgcn_exp2f(t);
    return x * __builtin_amdgcn_rcpf(1.0f + e);
}

// round-to-nearest-even f32 -> bf16 bits
__device__ __forceinline__ unsigned short f2bf(float x) {
    union { float f; unsigned u; } v; v.f = x;
    unsigned r = v.u + 0x7fffu + ((v.u >> 16) & 1u);
    return (unsigned short)(r >> 16);
}

// cheap round-half-up f32 -> bf16 bits (2 inst)
__device__ __forceinline__ unsigned short f2bf_rhu(float x) {
    union { float f; unsigned u; } v; v.f = x;
    return (unsigned short)((v.u + 0x8000u) >> 16);
}

// pack two f32 -> (bf16(a)<<16)|bf16(b), round-half-up: 2 adds + 1 v_perm
__device__ __forceinline__ unsigned pk_bf16(float a, float b) {
    union { float f; unsigned u; } ua, ub; ua.f = a; ub.f = b;
    return __builtin_amdgcn_perm(ua.u + 0x8000u, ub.u + 0x8000u, 0x07060302u);
}

// ---------------------------------------------------------------------------
// Kernel 0: pack fw1/fw2/hw1/hw2 into bf16 MFMA fragment order:
// dst[((kt*NT+nt)*64 + quad*16 + nc)*8 + j], kt=k>>5, quad=(k>>3)&3, j=k&7,
// nt=n>>4, nc=n&15.
// One thread packs a full j=0..7 fragment (16B write). Reads are
// row-coalesced (lanes span consecutive n), writes fully coalesced.
// ---------------------------------------------------------------------------
__global__ void pack_weights(const float* __restrict__ fw1,
                             const float* __restrict__ fw2,
                             const float* __restrict__ hw1,
                             const float* __restrict__ hw2,
                             unsigned short* __restrict__ fw1p,
                             unsigned short* __restrict__ fw2p,
                             unsigned short* __restrict__ hw1p,
                             unsigned short* __restrict__ hw2p) {
    int tid = blockIdx.x * 256 + threadIdx.x;
    const float* src; unsigned short* dst; int N, NT, idx;
    if (tid < 6144)        { src = fw1; dst = fw1p; N = ND;     NT = 24; idx = tid; }
    else if (tid < 24576)  { src = fw2; dst = fw2p; N = ND;     NT = 24; idx = tid - 6144; }
    else if (tid < 30720)  { src = hw1; dst = hw1p; N = NH;     NT = 8;  idx = tid - 24576; }
    else                   { src = hw2; dst = hw2p; N = NH / 2; NT = 4;  idx = tid - 30720; }
    int kg = idx / N;
    int n  = idx - kg * N;
    int k0 = kg * 8;
    int base = (((k0 >> 5) * NT + (n >> 4)) * 64 + ((k0 >> 3) & 3) * 16 + (n & 15)) * 8;
    short8 v;
    #pragma unroll
    for (int j = 0; j < 8; j++)
        v[j] = (short)f2bf(src[(size_t)(k0 + j) * N + n]);
    *(short8*)(dst + base) = v;
}

// ---------------------------------------------------------------------------
// Kernel 1: fused CFConv.  One block = 1 (b,l) group = 48 edge-rows.
// GEMM1 (transposed: D^T = fw1^T @ h_E^T) [384x128]@[128x48] -> gelu ->
// bf16 T via ds_write_b64 -> GEMM2 [48x384]@[384x384] (dbuf B prefetch) ->
// epilogue: bias+gelu -> W, gather x_j = h_V[E_idx], reduce over k.
// v3: Ea aliases T (LDS 37.9KB -> 4 blocks/CU), but launch_bounds kept at
// (256,3): v2's (256,4) squeezed VGPR 84->64 and spilled acc[18] to scratch
// (WRITE_SIZE 6MB->149MB). (256,3) gives ~84 VGPR; HW occupancy is still
// LDS-limited to 4 blocks/CU since 84 <= 128.
// ---------------------------------------------------------------------------
__global__ __launch_bounds__(256, 3) void cfconv_kernel(
    const float* __restrict__ h_V, const float* __restrict__ h_E,
    const float* __restrict__ fb1, const float* __restrict__ fb2,
    const unsigned short* __restrict__ fw1p,
    const unsigned short* __restrict__ fw2p,
    const int* __restrict__ E_idx, unsigned short* __restrict__ hbufB)
{
    // Single buffer, two phases:
    //   phase 1: Ea = h_E tile, 48 x 136 bf16 (6528 shorts)
    //   phase 2: T  = gelu(GEMM1) tile, 48 x 392 bf16 (18816 shorts)
    __shared__ unsigned short SH[48 * 392];
    __shared__ int rowoff_s[48];
    unsigned short* const Ea = SH;
    unsigned short* const T  = SH;

    const int t = threadIdx.x;
    const int wave = t >> 6, lane = t & 63;
    const int quad = lane >> 4, l16 = lane & 15;
    const int bl = blockIdx.x;
    const int wn0 = wave * 96;   // this wave's column slice of 384

    if (t < 48)
        rowoff_s[t] = ((bl >> 9) * NL + E_idx[bl * NK + t]) * ND;

    // stage h_E (48x128 f32) -> bf16 Ea
    {
        const float4* src = (const float4*)(h_E + (size_t)bl * (NK * NE));
        #pragma unroll
        for (int i = 0; i < 6; i++) {
            int v = i * 256 + t;         // 1536 float4
            float4 d = src[v];
            int r = v >> 5;              // 32 float4 per 128-col row
            int c = (v & 31) * 4;
            uint2 u;
            u.x = pk_bf16(d.y, d.x);
            u.y = pk_bf16(d.w, d.z);
            *(uint2*)&Ea[r * 136 + c] = u;
        }
    }
    __syncthreads();

    f32x4 acc[18];

    // ---- GEMM1 (transposed): M=n (wave slice 96, 6 mt), N=edge (48, 3 nt),
    //      K=128 (4 kt).  A = fw1^T from fw1p; B = h_E^T from Ea.
    #pragma unroll
    for (int i = 0; i < 18; i++) acc[i] = (f32x4){0.f, 0.f, 0.f, 0.f};

    #pragma unroll
    for (int kt = 0; kt < 4; kt++) {
        short8 aw[6], be[3];
        #pragma unroll
        for (int mt = 0; mt < 6; mt++)
            aw[mt] = *(const short8*)(fw1p + (size_t)((kt * 24 + (wn0 >> 4) + mt) * 64 + lane) * 8);
        #pragma unroll
        for (int nt = 0; nt < 3; nt++)
            be[nt] = *(const short8*)&Ea[(nt * 16 + l16) * 136 + kt * 32 + quad * 8];
        #pragma unroll
        for (int mt = 0; mt < 6; mt++)
            #pragma unroll
            for (int nt = 0; nt < 3; nt++)
                acc[mt * 3 + nt] = __builtin_amdgcn_mfma_f32_16x16x32_bf16(
                    aw[mt], be[nt], acc[mt * 3 + nt], 0, 0, 0);
    }

    // All Ea reads are done; T aliases Ea, so barrier before overwriting.
    __syncthreads();

    // epilogue1: +fb1, gelu -> T.  C/D of transposed GEMM1: col=edge (l16),
    // row = n-within-tile (quad*4+r): 4 consecutive n per lane -> b64 writes.
    #pragma unroll
    for (int mt = 0; mt < 6; mt++) {
        float4 b1v = *(const float4*)&fb1[wn0 + mt * 16 + quad * 4];
        #pragma unroll
        for (int nt = 0; nt < 3; nt++) {
            f32x4 a = acc[mt * 3 + nt];
            float v0 = gelu_fast(a[0] + b1v.x);
            float v1 = gelu_fast(a[1] + b1v.y);
            float v2 = gelu_fast(a[2] + b1v.z);
            float v3 = gelu_fast(a[3] + b1v.w);
            uint2 u;
            u.x = pk_bf16(v1, v0);
            u.y = pk_bf16(v3, v2);
            *(uint2*)&T[(nt * 16 + l16) * 392 + wn0 + mt * 16 + quad * 4] = u;
        }
    }
    __syncthreads();

    // ---- GEMM2: M=edge (48, 3 mt), N=wave slice 96 (6 nt), K=384 (12 kt),
    //      double-buffered B prefetch.
    #pragma unroll
    for (int i = 0; i < 18; i++) acc[i] = (f32x4){0.f, 0.f, 0.f, 0.f};

    {
        short8 b0[6], b1[6], af[3];
        #define LOADB(kt, bf)                                                            \
            _Pragma("unroll")                                                            \
            for (int nt = 0; nt < 6; nt++)                                               \
                bf[nt] = *(const short8*)(fw2p +                                         \
                    (size_t)(((kt) * 24 + (wn0 >> 4) + nt) * 64 + lane) * 8);
        #define LOADA(kt)                                                                \
            _Pragma("unroll")                                                            \
            for (int mt = 0; mt < 3; mt++)                                               \
                af[mt] = *(const short8*)&T[(mt * 16 + l16) * 392 + (kt) * 32 + quad * 8];
        #define MFMAS(bf)                                                                \
            _Pragma("unroll")                                                            \
            for (int mt = 0; mt < 3; mt++)                                               \
                _Pragma("unroll")                                                        \
                for (int nt = 0; nt < 6; nt++)                                           \
                    acc[nt * 3 + mt] = __builtin_amdgcn_mfma_f32_16x16x32_bf16(          \
                        af[mt], bf[nt], acc[nt * 3 + mt], 0, 0, 0);

        LOADB(0, b0);
        for (int kt = 0; kt < 10; kt += 2) {
            LOADB(kt + 1, b1);
            LOADA(kt);
            MFMAS(b0);
            LOADB(kt + 2, b0);
            LOADA(kt + 1);
            MFMAS(b1);
        }
        LOADB(11, b1);
        LOADA(10);
        MFMAS(b0);
        LOADA(11);
        MFMAS(b1);
        #undef LOADB
        #undef LOADA
        #undef MFMAS
    }

    // epilogue2: +fb2, gelu -> W; gather x_j; reduce over all 48 rows; store.
    float b2v[6];
    #pragma unroll
    for (int nt = 0; nt < 6; nt++) b2v[nt] = fb2[wn0 + nt * 16 + l16];

    float s[6] = {0.f, 0.f, 0.f, 0.f, 0.f, 0.f};
    #pragma unroll
    for (int mt = 0; mt < 3; mt++) {
        const int rb = mt * 16 + quad * 4;
        const float* p0 = h_V + rowoff_s[rb + 0] + wn0 + l16;
        const float* p1 = h_V + rowoff_s[rb + 1] + wn0 + l16;
        const float* p2 = h_V + rowoff_s[rb + 2] + wn0 + l16;
        const float* p3 = h_V + rowoff_s[rb + 3] + wn0 + l16;
        float xv[6][4];
        #pragma unroll
        for (int nt = 0; nt < 6; nt++) {
            xv[nt][0] = p0[nt * 16];
            xv[nt][1] = p1[nt * 16];
            xv[nt][2] = p2[nt * 16];
            xv[nt][3] = p3[nt * 16];
        }
        #pragma unroll
        for (int nt = 0; nt < 6; nt++)
            #pragma unroll
            for (int r = 0; r < 4; r++)
                s[nt] = fmaf(gelu_fast(acc[nt * 3 + mt][r] + b2v[nt]), xv[nt][r], s[nt]);
    }
    #pragma unroll
    for (int nt = 0; nt < 6; nt++) {
        float v = s[nt];
        v += __shfl_xor(v, 16, 64);
        v += __shfl_xor(v, 32, 64);
        if (lane < 16)
            hbufB[(size_t)bl * ND + wn0 + nt * 16 + lane] = f2bf(v);
    }
}

// ---------------------------------------------------------------------------
// Kernel 2: MLP head via MFMA.
// Two waves per 16-row tile (block=128 thr), splitting the N dimension:
// layer1 N=128 -> 64 cols/wave; layer2 N=64 -> 32 cols/wave; layer3 dot is
// split by column, combined via separability of the masked row-sum.
// ---------------------------------------------------------------------------
__global__ __launch_bounds__(128) void head_kernel(
    const unsigned short* __restrict__ hbufB,
    const unsigned short* __restrict__ hw1p, const float* __restrict__ hb1,
    const unsigned short* __restrict__ hw2p, const float* __restrict__ hb2,
    const float* __restrict__ hw3, const float* __restrict__ hb3,
    const float* __restrict__ mask, float* __restrict__ dGpart)
{
    __shared__ unsigned short T1[16 * 136];
    const int t = threadIdx.x;
    const int w = t >> 6;                 // wave id 0/1
    const int lane = t & 63;
    const int quad = lane >> 4, l16 = lane & 15;
    const int row0 = blockIdx.x * 16;

    // ---- layer1: K=384; this wave covers cols [w*64, w*64+64) ----
    f32x4 acc1[4];
    #pragma unroll
    for (int nt = 0; nt < 4; nt++) acc1[nt] = (f32x4){0.f, 0.f, 0.f, 0.f};

    for (int kt = 0; kt < 12; kt++) {
        short8 a = *(const short8*)(hbufB + (size_t)(row0 + l16) * ND + kt * 32 + quad * 8);
        #pragma unroll
        for (int nt = 0; nt < 4; nt++) {
            short8 b = *(const short8*)(hw1p + (size_t)((kt * 8 + w * 4 + nt) * 64 + lane) * 8);
            acc1[nt] = __builtin_amdgcn_mfma_f32_16x16x32_bf16(a, b, acc1[nt], 0, 0, 0);
        }
    }

    // gelu + bias -> T1 bf16 (waves write disjoint column halves)
    #pragma unroll
    for (int nt = 0; nt < 4; nt++) {
        int col = (w * 4 + nt) * 16 + l16;
        float b1 = hb1[col];
        #pragma unroll
        for (int r = 0; r < 4; r++)
            T1[(quad * 4 + r) * 136 + col] = f2bf_rhu(gelu_fast(acc1[nt][r] + b1));
    }
    __syncthreads();

    // ---- layer2: K=128; this wave covers cols [w*32, w*32+32) ----
    f32x4 acc2[2];
    #pragma unroll
    for (int nt = 0; nt < 2; nt++) acc2[nt] = (f32x4){0.f, 0.f, 0.f, 0.f};

    #pragma unroll
    for (int kt = 0; kt < 4; kt++) {
        short8 a = *(const short8*)&T1[l16 * 136 + kt * 32 + quad * 8];
        #pragma unroll
        for (int nt = 0; nt < 2; nt++) {
            short8 b = *(const short8*)(hw2p + (size_t)((kt * 4 + w * 2 + nt) * 64 + lane) * 8);
            acc2[nt] = __builtin_amdgcn_mfma_f32_16x16x32_bf16(a, b, acc2[nt], 0, 0, 0);
        }
    }

    // ---- layer3: gelu then partial 32-dot + masked accumulation ----
    float w3[2], b2[2];
    #pragma unroll
    for (int nt = 0; nt < 2; nt++) {
        int col = (w * 2 + nt) * 16 + l16;
        w3[nt] = hw3[col];
        b2[nt] = hb2[col];
    }

    float dsum = 0.f;
    const float hb3h = 0.5f * hb3[0];     // split evenly across the 2 waves
    #pragma unroll
    for (int r = 0; r < 4; r++) {
        float pr = 0.f;
        #pragma unroll
        for (int nt = 0; nt < 2; nt++)
            pr = fmaf(gelu_fast(acc2[nt][r] + b2[nt]), w3[nt], pr);
        pr += __shfl_xor(pr, 1, 64);
        pr += __shfl_xor(pr, 2, 64);
        pr += __shfl_xor(pr, 4, 64);
        pr += __shfl_xor(pr, 8, 64);
        if (l16 == 0) {
            int grow = row0 + quad * 4 + r;
            dsum = fmaf(pr + hb3h, mask[grow], dsum);
        }
    }
    dsum += __shfl_xor(dsum, 16, 64);
    dsum += __shfl_xor(dsum, 32, 64);
    if (lane == 0) dGpart[blockIdx.x * 2 + w] = dsum;
}

// ---------------------------------------------------------------------------
// Kernel 3: out[b] = sum(dGpart[b*64..b*64+64)) / sqrt(clip(sum(mask[b,:]),1))
// 256 threads: 16 lanes per batch
// ---------------------------------------------------------------------------
__global__ void finalize_kernel(const float* __restrict__ dGpart,
                                const float* __restrict__ mask,
                                float* __restrict__ out) {
    int t = threadIdx.x;
    int b = t >> 4, j = t & 15;
    float ms = 0.f;
    for (int l = j; l < NL; l += 16) ms += mask[b * NL + l];
    float dg = dGpart[b * 64 + j] + dGpart[b * 64 + 16 + j]
             + dGpart[b * 64 + 32 + j] + dGpart[b * 64 + 48 + j];
    #pragma unroll
    for (int d = 1; d < 16; d <<= 1) {
        ms += __shfl_xor(ms, d, 64);
        dg += __shfl_xor(dg, d, 64);
    }
    if (j == 0) {
        ms = fmaxf(ms, 1.0f);
        out[b] = dg / sqrtf(ms);
    }
}

extern "C" void kernel_launch(void* const* d_in, const int* in_sizes, int n_in,
                              void* d_out, int out_size, void* d_ws, size_t ws_size,
                              hipStream_t stream) {
    const float* h_V  = (const float*)d_in[0];
    const float* h_E  = (const float*)d_in[1];
    const float* mask = (const float*)d_in[2];
    const float* fw1  = (const float*)d_in[3];
    const float* fb1  = (const float*)d_in[4];
    const float* fw2  = (const float*)d_in[5];
    const float* fb2  = (const float*)d_in[6];
    const float* hw1  = (const float*)d_in[7];
    const float* hb1  = (const float*)d_in[8];
    const float* hw2  = (const float*)d_in[9];
    const float* hb2  = (const float*)d_in[10];
    const float* hw3  = (const float*)d_in[11];
    const float* hb3  = (const float*)d_in[12];
    const int*   E_idx = (const int*)d_in[13];
    float* out = (float*)d_out;

    char* ws = (char*)d_ws;
    unsigned short* fw1p = (unsigned short*)ws;              // 128*384*2 =  98304 B
    unsigned short* fw2p = (unsigned short*)(ws + 98304);    // 384*384*2 = 294912 B
    unsigned short* hw1p = (unsigned short*)(ws + 393216);   // 384*128*2 =  98304 B
    unsigned short* hw2p = (unsigned short*)(ws + 491520);   // 128*64*2  =  16384 B
    float* dGpart = (float*)(ws + 507904);                   // 1024*4 = 4096 B
    unsigned short* hbufB = (unsigned short*)(ws + 512000);  // 8192*384*2 = 6.3 MB

    pack_weights<<<124, 256, 0, stream>>>(fw1, fw2, hw1, hw2, fw1p, fw2p, hw1p, hw2p);
    cfconv_kernel<<<NB * NL, 256, 0, stream>>>(h_V, h_E, fb1, fb2, fw1p, fw2p, E_idx, hbufB);
    head_kernel<<<(NB * NL) / 16, 128, 0, stream>>>(hbufB, hw1p, hb1, hw2p, hb2, hw3, hb3, mask, dGpart);
    finalize_kernel<<<1, 256, 0, stream>>>(dGpart, mask, out);
}